// Round 1
// baseline (1061.471 us; speedup 1.0000x reference)
//
#include <hip/hip_runtime.h>
#include <stdint.h>

#define NWIN   4096
#define NTOK   49
#define NHEADS 8

typedef __attribute__((ext_vector_type(8))) short bf16x8;
typedef __attribute__((ext_vector_type(4))) float f32x4;

// ws layout (bytes)
#define OFF_Q    0LL
#define OFF_K    102760448LL
#define OFF_V    205520896LL
#define OFF_WQ   339738624LL
#define OFF_WP   340131840LL
#define OFF_RB   340262912LL

static __device__ __forceinline__ uint16_t f2bf(float f) {
    union { float f; uint32_t u; } v; v.f = f;
    return (uint16_t)((v.u + 0x7FFFu + ((v.u >> 16) & 1u)) >> 16);
}

static __device__ __forceinline__ f32x4 vmax4(f32x4 a, f32x4 b) {
    f32x4 r;
    r[0] = fmaxf(a[0], b[0]); r[1] = fmaxf(a[1], b[1]);
    r[2] = fmaxf(a[2], b[2]); r[3] = fmaxf(a[3], b[3]);
    return r;
}

// ---------------------------------------------------------------------------
// prep: weight fp32->bf16, rel-bias gather into [8][16][64][4] (padded -1e30),
//       zero v token-padding (toks 49..63)
// ---------------------------------------------------------------------------
__global__ void prep_kernel(const float* __restrict__ qkv_w, const float* __restrict__ proj_w,
                            const float* __restrict__ bias_table, const int* __restrict__ rel_index,
                            char* __restrict__ ws) {
    uint16_t* wq  = (uint16_t*)(ws + OFF_WQ);
    uint16_t* wp  = (uint16_t*)(ws + OFF_WP);
    float*    rb  = (float*)(ws + OFF_RB);
    uint16_t* vws = (uint16_t*)(ws + OFF_V);
    const int64_t T4 = (int64_t)NWIN * NHEADS * 32 * 15;
    const int64_t total = 196608 + 65536 + 32768 + T4;
    for (int64_t idx = (int64_t)blockIdx.x * blockDim.x + threadIdx.x; idx < total;
         idx += (int64_t)gridDim.x * blockDim.x) {
        if (idx < 196608) {
            wq[idx] = f2bf(qkv_w[idx]);
        } else if (idx < 262144) {
            int i = (int)idx - 196608;
            wp[i] = f2bf(proj_w[i]);
        } else if (idx < 294912) {
            int i = (int)idx - 262144;           // [8][64][64] logical
            int h = i >> 12, r = (i >> 6) & 63, c = i & 63;
            float v = -1e30f;
            if (r < NTOK && c < NTOK) v = bias_table[rel_index[r * NTOK + c] * NHEADS + h];
            rb[((h * 16 + (r >> 2)) * 64 + c) * 4 + (r & 3)] = v;   // [h][rq][c][rr]
        } else {
            int64_t i = idx - 294912;
            int64_t bhd = i / 15;
            int tok = 49 + (int)(i % 15);
            vws[bhd * 64 + tok] = 0;
        }
    }
}

// ---------------------------------------------------------------------------
// qkv: per block [64 tokens x 768 outs], K=256. x staged in LDS bf16 (+8 pad).
// Writes q,k as [b][h][49][32], v transposed as [b][h][32][64].
// ---------------------------------------------------------------------------
__global__ __launch_bounds__(256) void qkv_kernel(const float* __restrict__ x,
                                                  const float* __restrict__ qkv_b,
                                                  char* __restrict__ ws) {
    __shared__ __align__(16) uint16_t lds[64 * 264];
    const int t = threadIdx.x;
    const int m0 = blockIdx.x * 64;
    const float4* xv = (const float4*)x;
    #pragma unroll
    for (int it = 0; it < 16; ++it) {
        int f4 = it * 256 + t;
        int row = f4 >> 6, c4 = f4 & 63;
        float4 v = xv[(int64_t)(m0 + row) * 64 + c4];
        uint32_t lo = (uint32_t)f2bf(v.x) | ((uint32_t)f2bf(v.y) << 16);
        uint32_t hi = (uint32_t)f2bf(v.z) | ((uint32_t)f2bf(v.w) << 16);
        uint32_t* p = (uint32_t*)(lds + row * 264 + c4 * 4);
        p[0] = lo; p[1] = hi;
    }
    __syncthreads();
    const uint16_t* wq = (const uint16_t*)(ws + OFF_WQ);
    uint16_t* qws = (uint16_t*)(ws + OFF_Q);
    uint16_t* kws = (uint16_t*)(ws + OFF_K);
    uint16_t* vws = (uint16_t*)(ws + OFF_V);
    const int lane = t & 63, wave = t >> 6;
    const int wm = wave >> 1, wn = wave & 1;
    const int lr = lane & 15, lg = lane >> 4;
    for (int nIter = 0; nIter < 3; ++nIter) {
        const int colBase = nIter * 256 + wn * 128;
        f32x4 acc[2][8];
        #pragma unroll
        for (int mi = 0; mi < 2; ++mi)
            #pragma unroll
            for (int nj = 0; nj < 8; ++nj)
                acc[mi][nj] = (f32x4){0.f, 0.f, 0.f, 0.f};
        #pragma unroll
        for (int kk = 0; kk < 8; ++kk) {
            const int k0 = kk * 32;
            bf16x8 av[2];
            #pragma unroll
            for (int mi = 0; mi < 2; ++mi)
                av[mi] = *(const bf16x8*)(lds + (wm * 32 + mi * 16 + lr) * 264 + k0 + lg * 8);
            #pragma unroll
            for (int nj = 0; nj < 8; ++nj) {
                bf16x8 bv = *(const bf16x8*)(wq + (colBase + nj * 16 + lr) * 256 + k0 + lg * 8);
                acc[0][nj] = __builtin_amdgcn_mfma_f32_16x16x32_bf16(av[0], bv, acc[0][nj], 0, 0, 0);
                acc[1][nj] = __builtin_amdgcn_mfma_f32_16x16x32_bf16(av[1], bv, acc[1][nj], 0, 0, 0);
            }
        }
        #pragma unroll
        for (int nj = 0; nj < 8; ++nj) {
            const int n = colBase + nj * 16 + lr;
            const float bias = qkv_b[n];
            const int which = n >> 8, h = (n >> 5) & 7, d = n & 31;
            #pragma unroll
            for (int mi = 0; mi < 2; ++mi) {
                #pragma unroll
                for (int i = 0; i < 4; ++i) {
                    const int m = m0 + wm * 32 + mi * 16 + lg * 4 + i;
                    const int b = m / 49, tok = m - b * 49;
                    const uint16_t val = f2bf(acc[mi][nj][i] + bias);
                    if (which == 0)      qws[((b * 8 + h) * 49 + tok) * 32 + d] = val;
                    else if (which == 1) kws[((b * 8 + h) * 49 + tok) * 32 + d] = val;
                    else                 vws[((b * 8 + h) * 32 + d) * 64 + tok] = val;
                }
            }
        }
    }
}

// ---------------------------------------------------------------------------
// attn+proj fused: 1 block = 1 window, 4 waves x 2 heads, then proj GEMM.
// ---------------------------------------------------------------------------
__global__ __launch_bounds__(256) void attn_kernel(const float* __restrict__ proj_b,
                                                   float* __restrict__ out,
                                                   char* __restrict__ ws) {
    __shared__ __align__(16) char smem[65536];   // [0,32768) P per wave (8KB), [32768,65536) O tile
    const int b = blockIdx.x;
    const int t = threadIdx.x, lane = t & 63, wave = t >> 6;
    const int lr = lane & 15, lg = lane >> 4;
    const uint16_t* qws = (const uint16_t*)(ws + OFF_Q);
    const uint16_t* kws = (const uint16_t*)(ws + OFF_K);
    const uint16_t* vws = (const uint16_t*)(ws + OFF_V);
    const uint16_t* wp  = (const uint16_t*)(ws + OFF_WP);
    const float*    rb  = (const float*)(ws + OFF_RB);
    char* P  = smem + wave * 8192;
    char* OL = smem + 32768;
    const float scale = 0.17677669529663687f;

    #pragma unroll
    for (int hi = 0; hi < 2; ++hi) {
        const int h = wave + hi * 4;
        const int64_t bh = (int64_t)b * 8 + h;
        // direct global fragment loads (16B, coalesced across the wave)
        bf16x8 qf[4], kf[4];
        #pragma unroll
        for (int mi = 0; mi < 4; ++mi)
            qf[mi] = *(const bf16x8*)(qws + (bh * 49 + mi * 16 + lr) * 32 + lg * 8);
        #pragma unroll
        for (int nj = 0; nj < 4; ++nj)
            kf[nj] = *(const bf16x8*)(kws + (bh * 49 + nj * 16 + lr) * 32 + lg * 8);
        f32x4 s[4][4];
        #pragma unroll
        for (int mi = 0; mi < 4; ++mi)
            #pragma unroll
            for (int nj = 0; nj < 4; ++nj)
                s[mi][nj] = __builtin_amdgcn_mfma_f32_16x16x32_bf16(
                    qf[mi], kf[nj], (f32x4){0.f, 0.f, 0.f, 0.f}, 0, 0, 0);
        // scale + rel bias (float4 loads), row softmax (shfl over lr)
        f32x4 rm[4], rs[4];
        #pragma unroll
        for (int mi = 0; mi < 4; ++mi) {
            #pragma unroll
            for (int nj = 0; nj < 4; ++nj) {
                f32x4 bv = *(const f32x4*)(rb + ((h * 16 + mi * 4 + lg) * 64 + nj * 16 + lr) * 4);
                s[mi][nj] = s[mi][nj] * scale + bv;
            }
            rm[mi] = vmax4(vmax4(s[mi][0], s[mi][1]), vmax4(s[mi][2], s[mi][3]));
            #pragma unroll
            for (int c = 0; c < 4; ++c) {
                float v = rm[mi][c];
                v = fmaxf(v, __shfl_xor(v, 1));
                v = fmaxf(v, __shfl_xor(v, 2));
                v = fmaxf(v, __shfl_xor(v, 4));
                v = fmaxf(v, __shfl_xor(v, 8));
                rm[mi][c] = v;
            }
            #pragma unroll
            for (int nj = 0; nj < 4; ++nj)
                #pragma unroll
                for (int c = 0; c < 4; ++c)
                    s[mi][nj][c] = __expf(s[mi][nj][c] - rm[mi][c]);
            rs[mi] = s[mi][0] + s[mi][1] + s[mi][2] + s[mi][3];
            #pragma unroll
            for (int c = 0; c < 4; ++c) {
                float v = rs[mi][c];
                v += __shfl_xor(v, 1);
                v += __shfl_xor(v, 2);
                v += __shfl_xor(v, 4);
                v += __shfl_xor(v, 8);
                rs[mi][c] = v;
            }
        }
        // P (unnormalized, bf16) -> swizzled LDS
        #pragma unroll
        for (int mi = 0; mi < 4; ++mi)
            #pragma unroll
            for (int i = 0; i < 4; ++i) {
                const int row = mi * 16 + lg * 4 + i;
                const int swz = (row & 7) << 4;
                #pragma unroll
                for (int nj = 0; nj < 4; ++nj) {
                    const int col = nj * 16 + lr;
                    *(uint16_t*)(P + ((row * 128 + col * 2) ^ swz)) = f2bf(s[mi][nj][i]);
                }
            }
        // PV
        f32x4 o[4][2];
        #pragma unroll
        for (int mi = 0; mi < 4; ++mi)
            #pragma unroll
            for (int nj = 0; nj < 2; ++nj)
                o[mi][nj] = (f32x4){0.f, 0.f, 0.f, 0.f};
        #pragma unroll
        for (int ks = 0; ks < 2; ++ks) {
            bf16x8 pa[4];
            #pragma unroll
            for (int mi = 0; mi < 4; ++mi) {
                const int row = mi * 16 + lr;
                pa[mi] = *(const bf16x8*)(P + ((row * 128 + ks * 64 + lg * 16) ^ ((row & 7) << 4)));
            }
            #pragma unroll
            for (int nj = 0; nj < 2; ++nj) {
                bf16x8 vb = *(const bf16x8*)(vws + (bh * 32 + nj * 16 + lr) * 64 + ks * 32 + lg * 8);
                #pragma unroll
                for (int mi = 0; mi < 4; ++mi)
                    o[mi][nj] = __builtin_amdgcn_mfma_f32_16x16x32_bf16(pa[mi], vb, o[mi][nj], 0, 0, 0);
            }
        }
        // normalize, O -> swizzled LDS at cols h*32..h*32+31
        #pragma unroll
        for (int mi = 0; mi < 4; ++mi) {
            f32x4 rinv;
            #pragma unroll
            for (int c = 0; c < 4; ++c) rinv[c] = 1.0f / rs[mi][c];
            #pragma unroll
            for (int i = 0; i < 4; ++i) {
                const int row = mi * 16 + lg * 4 + i;
                const int swz = (row & 7) << 4;
                #pragma unroll
                for (int nj = 0; nj < 2; ++nj) {
                    const int col = h * 32 + nj * 16 + lr;
                    *(uint16_t*)(OL + ((row * 512 + col * 2) ^ swz)) = f2bf(o[mi][nj][i] * rinv[i]);
                }
            }
        }
    }
    __syncthreads();
    // proj: [64 x 256] @ [256 x 256]^T + b  -> out
    const int wm = wave >> 1, wn = wave & 1;
    f32x4 acc[2][8];
    #pragma unroll
    for (int mi = 0; mi < 2; ++mi)
        #pragma unroll
        for (int nj = 0; nj < 8; ++nj)
            acc[mi][nj] = (f32x4){0.f, 0.f, 0.f, 0.f};
    #pragma unroll
    for (int kk = 0; kk < 8; ++kk) {
        const int k0 = kk * 32;
        bf16x8 av[2];
        #pragma unroll
        for (int mi = 0; mi < 2; ++mi) {
            const int row = wm * 32 + mi * 16 + lr;
            av[mi] = *(const bf16x8*)(OL + ((row * 512 + k0 * 2 + lg * 16) ^ ((row & 7) << 4)));
        }
        #pragma unroll
        for (int nj = 0; nj < 8; ++nj) {
            bf16x8 bv = *(const bf16x8*)(wp + (wn * 128 + nj * 16 + lr) * 256 + k0 + lg * 8);
            acc[0][nj] = __builtin_amdgcn_mfma_f32_16x16x32_bf16(av[0], bv, acc[0][nj], 0, 0, 0);
            acc[1][nj] = __builtin_amdgcn_mfma_f32_16x16x32_bf16(av[1], bv, acc[1][nj], 0, 0, 0);
        }
    }
    #pragma unroll
    for (int nj = 0; nj < 8; ++nj) {
        const int n = wn * 128 + nj * 16 + lr;
        const float pb = proj_b[n];
        #pragma unroll
        for (int mi = 0; mi < 2; ++mi)
            #pragma unroll
            for (int i = 0; i < 4; ++i) {
                const int tok = wm * 32 + mi * 16 + lg * 4 + i;
                if (tok < 49)
                    out[((int64_t)b * 49 + tok) * 256 + n] = acc[mi][nj][i] + pb;
            }
    }
}

extern "C" void kernel_launch(void* const* d_in, const int* in_sizes, int n_in,
                              void* d_out, int out_size, void* d_ws, size_t ws_size,
                              hipStream_t stream) {
    const float* x          = (const float*)d_in[0];
    const float* qkv_w     = (const float*)d_in[1];
    const float* qkv_b     = (const float*)d_in[2];
    const float* proj_w    = (const float*)d_in[3];
    const float* proj_b    = (const float*)d_in[4];
    const float* bias_table = (const float*)d_in[5];
    const int*   rel_index  = (const int*)d_in[6];
    float* out = (float*)d_out;
    char*  ws  = (char*)d_ws;

    prep_kernel<<<8192, 256, 0, stream>>>(qkv_w, proj_w, bias_table, rel_index, ws);
    qkv_kernel<<<3136, 256, 0, stream>>>(x, qkv_b, ws);
    attn_kernel<<<4096, 256, 0, stream>>>(proj_b, out, ws);
}

// Round 2
// 516.979 us; speedup vs baseline: 2.0532x; 2.0532x over previous
//
#include <hip/hip_runtime.h>
#include <stdint.h>

#define NWIN 4096

typedef __attribute__((ext_vector_type(8))) short bf16x8;
typedef __attribute__((ext_vector_type(4))) float f32x4;

// ws layout (bytes): wq bf16 [768][256] @0 ; wp bf16 [256][256] @393216 ;
// rb f32 [8][16][64][4] @524288 (pad cols>=49 with -1e30)
#define OFF_WQ 0LL
#define OFF_WP 393216LL
#define OFF_RB 524288LL

static __device__ __forceinline__ uint32_t f2bf(float f) {
    union { float f; uint32_t u; } v; v.f = f;
    return (v.u + 0x7FFFu + ((v.u >> 16) & 1u)) >> 16;
}

static __device__ __forceinline__ f32x4 vmax4(f32x4 a, f32x4 b) {
    f32x4 r;
    r[0] = fmaxf(a[0], b[0]); r[1] = fmaxf(a[1], b[1]);
    r[2] = fmaxf(a[2], b[2]); r[3] = fmaxf(a[3], b[3]);
    return r;
}

// ---------------------------------------------------------------------------
// prep: weights fp32->bf16, rel-bias gather into [8][16][64][4] (cols>=49 -> -1e30)
// ---------------------------------------------------------------------------
__global__ void prep_kernel(const float* __restrict__ qkv_w, const float* __restrict__ proj_w,
                            const float* __restrict__ bias_table, const int* __restrict__ rel_index,
                            char* __restrict__ ws) {
    uint16_t* wq = (uint16_t*)(ws + OFF_WQ);
    uint16_t* wp = (uint16_t*)(ws + OFF_WP);
    float*    rb = (float*)(ws + OFF_RB);
    const int total = 196608 + 65536 + 32768;
    for (int idx = blockIdx.x * blockDim.x + threadIdx.x; idx < total;
         idx += gridDim.x * blockDim.x) {
        if (idx < 196608) {
            wq[idx] = (uint16_t)f2bf(qkv_w[idx]);
        } else if (idx < 262144) {
            int i = idx - 196608;
            wp[i] = (uint16_t)f2bf(proj_w[i]);
        } else {
            int i = idx - 262144;                 // [8][64][64] logical
            int h = i >> 12, r = (i >> 6) & 63, c = i & 63;
            float v = -1e30f;
            if (r < 49 && c < 49) v = bias_table[rel_index[r * 49 + c] * 8 + h];
            rb[((h * 16 + (r >> 2)) * 64 + c) * 4 + (r & 3)] = v;   // [h][rq][c][rr]
        }
    }
}

// ---------------------------------------------------------------------------
// fully fused: 1 block = 1 window, 8 waves = 8 heads.
//   phase1: qkv gemm (wave w -> head w cols) -> wave-local LDS
//   phase2: attention (no barrier needed: wave-local data)
//   phase3: O tile -> LDS (overlay x), proj gemm -> out
// ---------------------------------------------------------------------------
__global__ __launch_bounds__(512, 2) void fused_kernel(const float* __restrict__ x,
                                                       const float* __restrict__ qkv_b,
                                                       const float* __restrict__ proj_b,
                                                       float* __restrict__ out,
                                                       const char* __restrict__ ws) {
    __shared__ __align__(16) char smem[132096];
    // [0,33792):        X  [64][264] bf16 (rows 49..63 zero); later O [64][256] swz
    // [33792,+w*8192):  per-wave q [64][32] swz / k at +4096 ; P [64][64] swz overlays
    // [99328,+w*4096):  per-wave v [32][64] swz(d)
    const int b = blockIdx.x;
    const int t = threadIdx.x, lane = t & 63, w = t >> 6;
    const int lr = lane & 15, lg = lane >> 4;
    const uint16_t* wq = (const uint16_t*)(ws + OFF_WQ);
    const uint16_t* wp = (const uint16_t*)(ws + OFF_WP);
    const float*    rb = (const float*)(ws + OFF_RB);

    uint16_t* X  = (uint16_t*)smem;
    char*     QK = smem + 33792 + w * 8192;
    char*     V  = smem + 99328 + w * 4096;
    char*     OL = smem;
    const float scale = 0.17677669529663687f;

    // ---- stage x window -> LDS bf16 (64 rows, >=49 zeroed) ----
    {
        const float4* xv = (const float4*)x;
        #pragma unroll
        for (int it = 0; it < 8; ++it) {
            int idx = it * 512 + t;               // 4096 = 64 rows x 64 float4
            int row = idx >> 6, c4 = idx & 63;
            uint32_t lo = 0, hi = 0;
            if (row < 49) {
                float4 v4 = xv[((int64_t)b * 49 + row) * 64 + c4];
                lo = f2bf(v4.x) | (f2bf(v4.y) << 16);
                hi = f2bf(v4.z) | (f2bf(v4.w) << 16);
            }
            uint32_t* p = (uint32_t*)(X + row * 264 + c4 * 4);
            p[0] = lo; p[1] = hi;
        }
    }
    __syncthreads();

    // ---- phase 1: qkv gemm, wave w computes head w's 96 columns ----
    {
        f32x4 acc[4][6];
        #pragma unroll
        for (int mi = 0; mi < 4; ++mi)
            #pragma unroll
            for (int nj = 0; nj < 6; ++nj)
                acc[mi][nj] = (f32x4){0.f, 0.f, 0.f, 0.f};
        #pragma unroll
        for (int kk = 0; kk < 8; ++kk) {
            bf16x8 av[4];
            #pragma unroll
            for (int mi = 0; mi < 4; ++mi)
                av[mi] = *(const bf16x8*)(X + (mi * 16 + lr) * 264 + kk * 32 + lg * 8);
            #pragma unroll
            for (int nj = 0; nj < 6; ++nj) {
                const int n = (nj >> 1) * 256 + w * 32 + (nj & 1) * 16 + lr;
                bf16x8 bv = *(const bf16x8*)(wq + n * 256 + kk * 32 + lg * 8);
                #pragma unroll
                for (int mi = 0; mi < 4; ++mi)
                    acc[mi][nj] = __builtin_amdgcn_mfma_f32_16x16x32_bf16(av[mi], bv, acc[mi][nj], 0, 0, 0);
            }
        }
        // epilogue -> wave-local LDS
        #pragma unroll
        for (int nj = 0; nj < 6; ++nj) {
            const int sel = nj >> 1;
            const int d = (nj & 1) * 16 + lr;
            const float bias = qkv_b[sel * 256 + w * 32 + d];
            if (sel < 2) {
                char* dst = QK + sel * 4096;
                #pragma unroll
                for (int mi = 0; mi < 4; ++mi)
                    #pragma unroll
                    for (int i = 0; i < 4; ++i) {
                        const int tok = mi * 16 + lg * 4 + i;
                        *(uint16_t*)(dst + ((tok * 64 + d * 2) ^ ((tok & 7) << 4))) =
                            (uint16_t)f2bf(acc[mi][nj][i] + bias);
                    }
            } else {
                #pragma unroll
                for (int mi = 0; mi < 4; ++mi) {
                    const int tok0 = mi * 16 + lg * 4;
                    ushort4 pk;
                    pk.x = (uint16_t)f2bf(acc[mi][nj][0] + bias);
                    pk.y = (uint16_t)f2bf(acc[mi][nj][1] + bias);
                    pk.z = (uint16_t)f2bf(acc[mi][nj][2] + bias);
                    pk.w = (uint16_t)f2bf(acc[mi][nj][3] + bias);
                    *(ushort4*)(V + ((d * 128 + tok0 * 2) ^ ((d & 7) << 4))) = pk;
                }
            }
        }
    }

    // ---- phase 2: attention for head w (all wave-local, no barrier) ----
    f32x4 o[4][2];
    f32x4 rs[4];
    {
        bf16x8 qf[4], kf[4];
        #pragma unroll
        for (int mi = 0; mi < 4; ++mi) {
            const int row = mi * 16 + lr;
            qf[mi] = *(const bf16x8*)(QK + ((row * 64 + lg * 16) ^ ((row & 7) << 4)));
            kf[mi] = *(const bf16x8*)(QK + 4096 + ((row * 64 + lg * 16) ^ ((row & 7) << 4)));
        }
        f32x4 s[4][4];
        #pragma unroll
        for (int mi = 0; mi < 4; ++mi)
            #pragma unroll
            for (int nj = 0; nj < 4; ++nj)
                s[mi][nj] = __builtin_amdgcn_mfma_f32_16x16x32_bf16(
                    qf[mi], kf[nj], (f32x4){0.f, 0.f, 0.f, 0.f}, 0, 0, 0);
        f32x4 rm[4];
        #pragma unroll
        for (int mi = 0; mi < 4; ++mi) {
            #pragma unroll
            for (int nj = 0; nj < 4; ++nj) {
                f32x4 bv = *(const f32x4*)(rb + ((w * 16 + mi * 4 + lg) * 64 + nj * 16 + lr) * 4);
                s[mi][nj] = s[mi][nj] * scale + bv;
            }
            rm[mi] = vmax4(vmax4(s[mi][0], s[mi][1]), vmax4(s[mi][2], s[mi][3]));
            #pragma unroll
            for (int c = 0; c < 4; ++c) {
                float v = rm[mi][c];
                v = fmaxf(v, __shfl_xor(v, 1));
                v = fmaxf(v, __shfl_xor(v, 2));
                v = fmaxf(v, __shfl_xor(v, 4));
                v = fmaxf(v, __shfl_xor(v, 8));
                rm[mi][c] = v;
            }
            #pragma unroll
            for (int nj = 0; nj < 4; ++nj)
                #pragma unroll
                for (int c = 0; c < 4; ++c)
                    s[mi][nj][c] = __expf(s[mi][nj][c] - rm[mi][c]);
            rs[mi] = s[mi][0] + s[mi][1] + s[mi][2] + s[mi][3];
            #pragma unroll
            for (int c = 0; c < 4; ++c) {
                float v = rs[mi][c];
                v += __shfl_xor(v, 1);
                v += __shfl_xor(v, 2);
                v += __shfl_xor(v, 4);
                v += __shfl_xor(v, 8);
                rs[mi][c] = v;
            }
        }
        // P (unnormalized bf16) overlays q/k (wave-local; data deps keep order)
        char* P = QK;
        #pragma unroll
        for (int mi = 0; mi < 4; ++mi)
            #pragma unroll
            for (int i = 0; i < 4; ++i) {
                const int row = mi * 16 + lg * 4 + i;
                const int swz = (row & 7) << 4;
                #pragma unroll
                for (int nj = 0; nj < 4; ++nj)
                    *(uint16_t*)(P + ((row * 128 + (nj * 16 + lr) * 2) ^ swz)) =
                        (uint16_t)f2bf(s[mi][nj][i]);
            }
        // PV
        #pragma unroll
        for (int mi = 0; mi < 4; ++mi)
            #pragma unroll
            for (int nj = 0; nj < 2; ++nj)
                o[mi][nj] = (f32x4){0.f, 0.f, 0.f, 0.f};
        #pragma unroll
        for (int ks = 0; ks < 2; ++ks) {
            bf16x8 pa[4];
            #pragma unroll
            for (int mi = 0; mi < 4; ++mi) {
                const int row = mi * 16 + lr;
                pa[mi] = *(const bf16x8*)(P + ((row * 128 + ks * 64 + lg * 16) ^ ((row & 7) << 4)));
            }
            #pragma unroll
            for (int nj = 0; nj < 2; ++nj) {
                const int dv = nj * 16 + lr;
                bf16x8 vb = *(const bf16x8*)(V + ((dv * 128 + ks * 64 + lg * 16) ^ ((dv & 7) << 4)));
                #pragma unroll
                for (int mi = 0; mi < 4; ++mi)
                    o[mi][nj] = __builtin_amdgcn_mfma_f32_16x16x32_bf16(pa[mi], vb, o[mi][nj], 0, 0, 0);
            }
        }
    }

    // ---- phase 3: O -> LDS (overlay X), proj gemm ----
    __syncthreads();
    #pragma unroll
    for (int mi = 0; mi < 4; ++mi) {
        f32x4 rinv;
        #pragma unroll
        for (int c = 0; c < 4; ++c) rinv[c] = 1.0f / rs[mi][c];
        #pragma unroll
        for (int i = 0; i < 4; ++i) {
            const int row = mi * 16 + lg * 4 + i;
            const int swz = (row & 7) << 4;
            #pragma unroll
            for (int nj = 0; nj < 2; ++nj) {
                const int col = w * 32 + nj * 16 + lr;
                *(uint16_t*)(OL + ((row * 512 + col * 2) ^ swz)) =
                    (uint16_t)f2bf(o[mi][nj][i] * rinv[i]);
            }
        }
    }
    __syncthreads();

    const int wm = w >> 2, wn = w & 3;
    f32x4 pacc[2][4];
    #pragma unroll
    for (int mi = 0; mi < 2; ++mi)
        #pragma unroll
        for (int nj = 0; nj < 4; ++nj)
            pacc[mi][nj] = (f32x4){0.f, 0.f, 0.f, 0.f};
    #pragma unroll
    for (int kk = 0; kk < 8; ++kk) {
        bf16x8 av[2];
        #pragma unroll
        for (int mi = 0; mi < 2; ++mi) {
            const int row = wm * 32 + mi * 16 + lr;
            av[mi] = *(const bf16x8*)(OL + ((row * 512 + kk * 64 + lg * 16) ^ ((row & 7) << 4)));
        }
        #pragma unroll
        for (int nj = 0; nj < 4; ++nj) {
            bf16x8 bv = *(const bf16x8*)(wp + (wn * 64 + nj * 16 + lr) * 256 + kk * 32 + lg * 8);
            #pragma unroll
            for (int mi = 0; mi < 2; ++mi)
                pacc[mi][nj] = __builtin_amdgcn_mfma_f32_16x16x32_bf16(av[mi], bv, pacc[mi][nj], 0, 0, 0);
        }
    }
    #pragma unroll
    for (int nj = 0; nj < 4; ++nj) {
        const int n = wn * 64 + nj * 16 + lr;
        const float pb = proj_b[n];
        #pragma unroll
        for (int mi = 0; mi < 2; ++mi)
            #pragma unroll
            for (int i = 0; i < 4; ++i) {
                const int tok = wm * 32 + mi * 16 + lg * 4 + i;
                if (tok < 49)
                    out[((int64_t)b * 49 + tok) * 256 + n] = pacc[mi][nj][i] + pb;
            }
    }
}

extern "C" void kernel_launch(void* const* d_in, const int* in_sizes, int n_in,
                              void* d_out, int out_size, void* d_ws, size_t ws_size,
                              hipStream_t stream) {
    const float* x          = (const float*)d_in[0];
    const float* qkv_w      = (const float*)d_in[1];
    const float* qkv_b      = (const float*)d_in[2];
    const float* proj_w     = (const float*)d_in[3];
    const float* proj_b     = (const float*)d_in[4];
    const float* bias_table = (const float*)d_in[5];
    const int*   rel_index  = (const int*)d_in[6];
    float* out = (float*)d_out;
    char*  ws  = (char*)d_ws;

    prep_kernel<<<1152, 256, 0, stream>>>(qkv_w, proj_w, bias_table, rel_index, ws);
    fused_kernel<<<NWIN, 512, 0, stream>>>(x, qkv_b, proj_b, out, ws);
}